// Round 2
// baseline (16524.254 us; speedup 1.0000x reference)
//
#include <hip/hip_runtime.h>

// nBRC recurrent cell, B=64, L=512, IN=512, MEM=1024.
//   Phase 1: E[32768][3072] = u(32768x512) @ W_im^T(512x3072), bf16x3 split precision MFMA.
//   Phase 2: 512-step scan, persistent kernel (plain launch, grid=256=#CUs so all
//            blocks are co-resident by construction), one custom grid barrier per step.
// Workspace layout (bytes):
//   [0, 402653184)            E (fp32)
//   [402653184, 403177472)    hbuf: [2 pingpong][2 planes hi/lo][64][1024] bf16 bits
//   [403177472, +8)           barrier {count, generation}
// Precision: all GEMMs computed as hi*hi + lo*hi + hi*lo with bf16 hi/lo splits,
// fp32 accumulation; h carried in fp32 thread registers. Expected absmax ~1e-3.

typedef __attribute__((ext_vector_type(8))) short short8;
typedef __attribute__((ext_vector_type(4))) float floatx4;

#define WS_HBUF_OFF 402653184UL
#define WS_BAR_OFF  403177472UL

__device__ __forceinline__ unsigned short f2bf(float x) {
  unsigned u = __float_as_uint(x);
  unsigned r = (u + 0x7fffu + ((u >> 16) & 1u)) >> 16;  // RTN-even
  return (unsigned short)r;
}
__device__ __forceinline__ float bf2f(unsigned short h) {
  return __uint_as_float(((unsigned)h) << 16);
}

// ---------------------------------------------------------------------------
// Phase 1: E = U (32768x512, K-major) @ Wim^T (3072x512, K-major), fp32 out.
// 128x128 tile, BK=32, 4 waves in 2x2, each wave 64x64 via 4x4 mfma_16x16x32.
// +8 bf16 pad per LDS row -> 2-way (free) bank aliasing on ds_read_b128.
// ---------------------------------------------------------------------------
__global__ void __launch_bounds__(256, 2) gemm_in_proj(
    const float* __restrict__ U, const float* __restrict__ Wim,
    float* __restrict__ E)
{
  __shared__ unsigned short Ah[128][40], Al[128][40], Bh[128][40], Bl[128][40];
  const int tid = threadIdx.x;
  const int rbase = blockIdx.x * 128;   // M tiles: 32768/128 = 256
  const int nbase = blockIdx.y * 128;   // N tiles: 3072/128 = 24
  const int wave = tid >> 6, lane = tid & 63;
  const int wm = wave & 1, wn = wave >> 1;
  const int q = lane >> 4, ln = lane & 15;

  floatx4 acc[4][4];
#pragma unroll
  for (int mt = 0; mt < 4; ++mt)
#pragma unroll
    for (int nt = 0; nt < 4; ++nt)
      acc[mt][nt] = (floatx4){0.f, 0.f, 0.f, 0.f};

  for (int kc = 0; kc < 16; ++kc) {           // K = 512 = 16 * 32
    __syncthreads();
    // stage A (u rows) and B (W_im rows): fp32 -> hi/lo bf16 in LDS
#pragma unroll
    for (int i = tid; i < 1024; i += 256) {   // 128 rows x 8 float4
      const int row = i >> 3, c4 = (i & 7) << 2;
      const float4 va = *(const float4*)(U + (rbase + row) * 512 + kc * 32 + c4);
      const unsigned short a0 = f2bf(va.x), a1 = f2bf(va.y), a2 = f2bf(va.z), a3 = f2bf(va.w);
      *(ushort4*)&Ah[row][c4] = make_ushort4(a0, a1, a2, a3);
      *(ushort4*)&Al[row][c4] = make_ushort4(f2bf(va.x - bf2f(a0)), f2bf(va.y - bf2f(a1)),
                                             f2bf(va.z - bf2f(a2)), f2bf(va.w - bf2f(a3)));
      const float4 vb = *(const float4*)(Wim + (nbase + row) * 512 + kc * 32 + c4);
      const unsigned short b0 = f2bf(vb.x), b1 = f2bf(vb.y), b2 = f2bf(vb.z), b3 = f2bf(vb.w);
      *(ushort4*)&Bh[row][c4] = make_ushort4(b0, b1, b2, b3);
      *(ushort4*)&Bl[row][c4] = make_ushort4(f2bf(vb.x - bf2f(b0)), f2bf(vb.y - bf2f(b1)),
                                             f2bf(vb.z - bf2f(b2)), f2bf(vb.w - bf2f(b3)));
    }
    __syncthreads();

    short8 ah[4], al[4], bh[4], bl2[4];
#pragma unroll
    for (int mt = 0; mt < 4; ++mt) {
      const int m = wm * 64 + mt * 16 + ln;
      ah[mt] = *(const short8*)&Ah[m][q * 8];
      al[mt] = *(const short8*)&Al[m][q * 8];
    }
#pragma unroll
    for (int nt = 0; nt < 4; ++nt) {
      const int n = wn * 64 + nt * 16 + ln;
      bh[nt]  = *(const short8*)&Bh[n][q * 8];
      bl2[nt] = *(const short8*)&Bl[n][q * 8];
    }
#pragma unroll
    for (int mt = 0; mt < 4; ++mt)
#pragma unroll
      for (int nt = 0; nt < 4; ++nt) {
        acc[mt][nt] = __builtin_amdgcn_mfma_f32_16x16x32_bf16(ah[mt], bh[nt],  acc[mt][nt], 0, 0, 0);
        acc[mt][nt] = __builtin_amdgcn_mfma_f32_16x16x32_bf16(al[mt], bh[nt],  acc[mt][nt], 0, 0, 0);
        acc[mt][nt] = __builtin_amdgcn_mfma_f32_16x16x32_bf16(ah[mt], bl2[nt], acc[mt][nt], 0, 0, 0);
      }
  }

  // C/D layout (m89-verified): col = lane&15, row = quad*4 + reg
#pragma unroll
  for (int mt = 0; mt < 4; ++mt)
#pragma unroll
    for (int nt = 0; nt < 4; ++nt)
#pragma unroll
      for (int r = 0; r < 4; ++r) {
        const int gm = rbase + wm * 64 + mt * 16 + q * 4 + r;
        const int gn = nbase + wn * 64 + nt * 16 + ln;
        E[gm * 3072 + gn] = acc[mt][nt][r];
      }
}

// ---------------------------------------------------------------------------
// Grid barrier: sense-free generation barrier, device-scope.
// __threadfence() on both sides handles cross-XCD visibility (wbl2/inv).
// ---------------------------------------------------------------------------
__device__ __forceinline__ void grid_barrier(unsigned* bar, unsigned nb, int tid)
{
  __syncthreads();               // all wg stores issued & drained before arrival
  if (tid == 0) {
    __threadfence();             // release: flush dirty L2 (cross-XCD h state)
    unsigned* cnt = bar;
    unsigned* gen = bar + 1;
    const unsigned g = __hip_atomic_load(gen, __ATOMIC_RELAXED, __HIP_MEMORY_SCOPE_AGENT);
    const unsigned arrived =
        __hip_atomic_fetch_add(cnt, 1u, __ATOMIC_ACQ_REL, __HIP_MEMORY_SCOPE_AGENT) + 1u;
    if (arrived == nb) {
      __hip_atomic_store(cnt, 0u, __ATOMIC_RELAXED, __HIP_MEMORY_SCOPE_AGENT);
      __hip_atomic_fetch_add(gen, 1u, __ATOMIC_RELEASE, __HIP_MEMORY_SCOPE_AGENT);
    } else {
      while (__hip_atomic_load(gen, __ATOMIC_RELAXED, __HIP_MEMORY_SCOPE_AGENT) == g)
        __builtin_amdgcn_s_sleep(2);
    }
    __threadfence();             // acquire: invalidate stale L1/L2 lines
  }
  __syncthreads();
}

// ---------------------------------------------------------------------------
// Phase 2: persistent scan. Plain launch, 256 wgs x 256 thr. grid == #CUs and
// resources are tiny (4.4 KB LDS, 4 waves), so every wg is co-resident on its
// own CU by construction -> the spin barrier cannot deadlock.
// wg = (bg in 2)x(cg in 128): batches [bg*32,+32), col-pairs [cg*8,+8)
//   -> 16 W_mm rows (8 a-rows j0..j0+7, 8 c-rows 1024+j0..+7), held hi/lo in VGPRs.
// 4 waves = (mt batch-half 16) x (kh K-half 512); K-split partials reduced via LDS.
// h state: fp32 in registers (owner thread), broadcast via global bf16 hi/lo ping-pong.
// ---------------------------------------------------------------------------
__global__ void __launch_bounds__(256, 1) rnn_scan(
    const float* __restrict__ E,
    const float* __restrict__ Wmm,
    unsigned short* __restrict__ hbuf,   // [2][2][64][1024] bf16 bits
    float* __restrict__ out,
    unsigned* __restrict__ bar)
{
  __shared__ float part[4 * 16 * 17];    // [kh*2+mt][m 16][n 16 (+1 pad)]

  const int tid  = threadIdx.x;
  const int bg   = blockIdx.x >> 7;      // 0..1
  const int cg   = blockIdx.x & 127;     // 0..127
  const int b0   = bg << 5;              // batch base
  const int j0   = cg << 3;              // column base

  const int wave = tid >> 6, lane = tid & 63;
  const int q = lane >> 4, ln = lane & 15;
  const int mt = wave & 1, kh = wave >> 1;

  // --- preload this wave's W_mm fragments (hi/lo bf16) into registers ---
  short8 wh[16], wl[16];
  {
    const int grow = (ln < 8) ? (j0 + ln) : (1024 + j0 + (ln - 8));
    const float* wp = Wmm + grow * 1024 + kh * 512 + q * 8;
#pragma unroll
    for (int ks = 0; ks < 16; ++ks) {
      const float4 v0 = *(const float4*)(wp + ks * 32);
      const float4 v1 = *(const float4*)(wp + ks * 32 + 4);
      float f[8];
      f[0] = v0.x; f[1] = v0.y; f[2] = v0.z; f[3] = v0.w;
      f[4] = v1.x; f[5] = v1.y; f[6] = v1.z; f[7] = v1.w;
      short8 h8, l8;
#pragma unroll
      for (int e = 0; e < 8; ++e) {
        const unsigned short hh = f2bf(f[e]);
        h8[e] = (short)hh;
        l8[e] = (short)f2bf(f[e] - bf2f(hh));
      }
      wh[ks] = h8; wl[ks] = l8;
    }
  }

  // update-phase ownership: one (b, j) per thread
  const int bl = tid >> 3, jl = tid & 7;     // bl 0..31, jl 0..7
  const int b = b0 + bl, j = j0 + jl;
  const int mtu = bl >> 4, mlu = bl & 15;

  float h_reg = 0.0f;
  const int arow_base = (b0 + mt * 16 + ln) * 1024 + kh * 512 + q * 8;

  for (int t = 0; t < 512; ++t) {
    const int cur = t & 1, nxt = cur ^ 1;

    // prefetch this thread's input-projection terms (in flight during MFMA)
    const int erow = (b * 512 + t) * 3072 + j;
    const float ia = E[erow];
    const float ic = E[erow + 1024];
    const float io = E[erow + 2048];

    const unsigned short* Hh = hbuf + cur * 131072;
    const unsigned short* Hl = Hh + 65536;

    floatx4 acc = (floatx4){0.f, 0.f, 0.f, 0.f};
#pragma unroll
    for (int ks = 0; ks < 16; ++ks) {
      const short8 ahi = *(const short8*)(Hh + arow_base + ks * 32);
      const short8 alo = *(const short8*)(Hl + arow_base + ks * 32);
      acc = __builtin_amdgcn_mfma_f32_16x16x32_bf16(ahi, wh[ks], acc, 0, 0, 0);
      acc = __builtin_amdgcn_mfma_f32_16x16x32_bf16(alo, wh[ks], acc, 0, 0, 0);
      acc = __builtin_amdgcn_mfma_f32_16x16x32_bf16(ahi, wl[ks], acc, 0, 0, 0);
    }
    {
      const int slab = (kh * 2 + mt) * 16;
#pragma unroll
      for (int r = 0; r < 4; ++r)
        part[(slab + q * 4 + r) * 17 + ln] = acc[r];
    }
    __syncthreads();

    // reduce K-halves; a-part at n=jl, c-part at n=8+jl
    const float m_a = part[((0 + mtu) * 16 + mlu) * 17 + jl]
                    + part[((2 + mtu) * 16 + mlu) * 17 + jl];
    const float m_c = part[((0 + mtu) * 16 + mlu) * 17 + 8 + jl]
                    + part[((2 + mtu) * 16 + mlu) * 17 + 8 + jl];

    const float av = 1.0f + tanhf(ia + m_a);
    const float cv = 1.0f / (1.0f + expf(-(ic + m_c)));
    const float hn = cv * h_reg + (1.0f - cv) * tanhf(io + av * h_reg);
    h_reg = hn;

    out[(b * 512 + t) * 1024 + j] = hn;
    const unsigned short hh = f2bf(hn);
    unsigned short* Nh = hbuf + nxt * 131072;
    Nh[b * 1024 + j] = hh;
    Nh[65536 + b * 1024 + j] = f2bf(hn - bf2f(hh));

    grid_barrier(bar, gridDim.x, tid);
  }

  // second output: h at t = L-1
  out[33554432 + b * 1024 + j] = h_reg;
}

// ---------------------------------------------------------------------------
extern "C" void kernel_launch(void* const* d_in, const int* in_sizes, int n_in,
                              void* d_out, int out_size, void* d_ws, size_t ws_size,
                              hipStream_t stream)
{
  const float* U   = (const float*)d_in[0];   // (64,512,512)
  const float* Wim = (const float*)d_in[1];   // (3072,512)
  const float* Wmm = (const float*)d_in[2];   // (2048,1024)
  float* out = (float*)d_out;                 // 33,554,432 + 65,536 fp32
  char* ws = (char*)d_ws;

  float* E = (float*)ws;
  unsigned short* hbuf = (unsigned short*)(ws + WS_HBUF_OFF);
  unsigned* bar = (unsigned*)(ws + WS_BAR_OFF);

  // zero h ping-pong buffers (h0 = 0) and barrier state (ws is poisoned 0xAA)
  hipMemsetAsync((void*)hbuf, 0, 524288 + 64, stream);

  gemm_in_proj<<<dim3(256, 24), dim3(256), 0, stream>>>(U, Wim, E);

  rnn_scan<<<dim3(256), dim3(256), 0, stream>>>(E, Wmm, hbuf, out, bar);
}

// Round 3
// 13182.590 us; speedup vs baseline: 1.2535x; 1.2535x over previous
//
#include <hip/hip_runtime.h>

// nBRC recurrent cell, B=64, L=512, IN=512, MEM=1024.
// Phase 1: E[32768][3072] = u @ W_im^T, bf16x3 split-precision MFMA (unchanged).
// Phase 2: 512-step scan, persistent kernel, 256 blocks = 4 independent sync
//   groups of 64 (group g owns batches [g*16, g*16+16), all 2048 W_mm rows).
//   Block (bg,cg): 16 batches x 32 W-rows (16 a-rows j0..j0+15, 16 c-rows
//   1024+j0..+15), W held hi/lo bf16 in VGPRs (128 VGPR/lane).
//   h state: packed uint32 (bf16 hi | lo<<16), global ping-pong; per-group
//   counter barrier per step (64 blocks, not 256).
// Workspace layout (bytes):
//   [0, 402653184)            E (fp32)
//   [402653184, +524288)      hbuf: [2 pingpong][64][1024] packed uint32
//   [403177472, +256)         4x {count, generation} barriers, 64B apart
// Precision: GEMMs = hi*hi + lo*hi + hi*lo (bf16 splits), fp32 accum; h carried
// fp32 in owner registers. Measured absmax 3.9e-3 with this numerics path.

typedef __attribute__((ext_vector_type(8))) short short8;
typedef __attribute__((ext_vector_type(4))) float floatx4;

#define WS_HBUF_OFF 402653184UL
#define WS_BAR_OFF  403177472UL

__device__ __forceinline__ unsigned short f2bf(float x) {
  unsigned u = __float_as_uint(x);
  unsigned r = (u + 0x7fffu + ((u >> 16) & 1u)) >> 16;  // RTN-even
  return (unsigned short)r;
}
__device__ __forceinline__ float bf2f(unsigned short h) {
  return __uint_as_float(((unsigned)h) << 16);
}

// ---------------------------------------------------------------------------
// Phase 1: E = U (32768x512, K-major) @ Wim^T (3072x512, K-major), fp32 out.
// ---------------------------------------------------------------------------
__global__ void __launch_bounds__(256, 2) gemm_in_proj(
    const float* __restrict__ U, const float* __restrict__ Wim,
    float* __restrict__ E)
{
  __shared__ unsigned short Ah[128][40], Al[128][40], Bh[128][40], Bl[128][40];
  const int tid = threadIdx.x;
  const int rbase = blockIdx.x * 128;
  const int nbase = blockIdx.y * 128;
  const int wave = tid >> 6, lane = tid & 63;
  const int wm = wave & 1, wn = wave >> 1;
  const int q = lane >> 4, ln = lane & 15;

  floatx4 acc[4][4];
#pragma unroll
  for (int mt = 0; mt < 4; ++mt)
#pragma unroll
    for (int nt = 0; nt < 4; ++nt)
      acc[mt][nt] = (floatx4){0.f, 0.f, 0.f, 0.f};

  for (int kc = 0; kc < 16; ++kc) {
    __syncthreads();
#pragma unroll
    for (int i = tid; i < 1024; i += 256) {
      const int row = i >> 3, c4 = (i & 7) << 2;
      const float4 va = *(const float4*)(U + (rbase + row) * 512 + kc * 32 + c4);
      const unsigned short a0 = f2bf(va.x), a1 = f2bf(va.y), a2 = f2bf(va.z), a3 = f2bf(va.w);
      *(ushort4*)&Ah[row][c4] = make_ushort4(a0, a1, a2, a3);
      *(ushort4*)&Al[row][c4] = make_ushort4(f2bf(va.x - bf2f(a0)), f2bf(va.y - bf2f(a1)),
                                             f2bf(va.z - bf2f(a2)), f2bf(va.w - bf2f(a3)));
      const float4 vb = *(const float4*)(Wim + (nbase + row) * 512 + kc * 32 + c4);
      const unsigned short b0 = f2bf(vb.x), b1 = f2bf(vb.y), b2 = f2bf(vb.z), b3 = f2bf(vb.w);
      *(ushort4*)&Bh[row][c4] = make_ushort4(b0, b1, b2, b3);
      *(ushort4*)&Bl[row][c4] = make_ushort4(f2bf(vb.x - bf2f(b0)), f2bf(vb.y - bf2f(b1)),
                                             f2bf(vb.z - bf2f(b2)), f2bf(vb.w - bf2f(b3)));
    }
    __syncthreads();

    short8 ah[4], al[4], bh[4], bl2[4];
#pragma unroll
    for (int mt = 0; mt < 4; ++mt) {
      const int m = wm * 64 + mt * 16 + ln;
      ah[mt] = *(const short8*)&Ah[m][q * 8];
      al[mt] = *(const short8*)&Al[m][q * 8];
    }
#pragma unroll
    for (int nt = 0; nt < 4; ++nt) {
      const int n = wn * 64 + nt * 16 + ln;
      bh[nt]  = *(const short8*)&Bh[n][q * 8];
      bl2[nt] = *(const short8*)&Bl[n][q * 8];
    }
#pragma unroll
    for (int mt = 0; mt < 4; ++mt)
#pragma unroll
      for (int nt = 0; nt < 4; ++nt) {
        acc[mt][nt] = __builtin_amdgcn_mfma_f32_16x16x32_bf16(ah[mt], bh[nt],  acc[mt][nt], 0, 0, 0);
        acc[mt][nt] = __builtin_amdgcn_mfma_f32_16x16x32_bf16(al[mt], bh[nt],  acc[mt][nt], 0, 0, 0);
        acc[mt][nt] = __builtin_amdgcn_mfma_f32_16x16x32_bf16(ah[mt], bl2[nt], acc[mt][nt], 0, 0, 0);
      }
  }

#pragma unroll
  for (int mt = 0; mt < 4; ++mt)
#pragma unroll
    for (int nt = 0; nt < 4; ++nt)
#pragma unroll
      for (int r = 0; r < 4; ++r) {
        const int gm = rbase + wm * 64 + mt * 16 + q * 4 + r;
        const int gn = nbase + wn * 64 + nt * 16 + ln;
        E[gm * 3072 + gn] = acc[mt][nt][r];
      }
}

// ---------------------------------------------------------------------------
// Per-group barrier (64 blocks). Proven structure from round 2, nb=64.
// __threadfence release/acquire handles cross-XCD visibility of plain stores.
// ---------------------------------------------------------------------------
__device__ __forceinline__ void group_barrier(unsigned* bar, unsigned nb, int tid)
{
  __syncthreads();               // all waves drain their stores to L2 first
  if (tid == 0) {
    __threadfence();             // release: wbl2 — dirty L2 -> coherent point
    unsigned* cnt = bar;
    unsigned* gen = bar + 1;
    const unsigned g = __hip_atomic_load(gen, __ATOMIC_RELAXED, __HIP_MEMORY_SCOPE_AGENT);
    const unsigned arrived =
        __hip_atomic_fetch_add(cnt, 1u, __ATOMIC_ACQ_REL, __HIP_MEMORY_SCOPE_AGENT) + 1u;
    if (arrived == nb) {
      __hip_atomic_store(cnt, 0u, __ATOMIC_RELAXED, __HIP_MEMORY_SCOPE_AGENT);
      __hip_atomic_fetch_add(gen, 1u, __ATOMIC_RELEASE, __HIP_MEMORY_SCOPE_AGENT);
    } else {
      while (__hip_atomic_load(gen, __ATOMIC_RELAXED, __HIP_MEMORY_SCOPE_AGENT) == g)
        __builtin_amdgcn_s_sleep(1);
    }
    __threadfence();             // acquire: inv — L1/L2 stale lines dropped
  }
  __syncthreads();
}

// ---------------------------------------------------------------------------
// Phase 2: persistent scan. 256 blocks x 256 thr, 1 block/CU (co-resident by
// construction). bg = blockIdx>>6 (4 groups), cg = blockIdx&63.
// Block: batches [bg*16,+16), W-rows {j0..j0+15, 1024+j0..+15}, j0 = cg*16.
// Waves = 4 k-quarters (256 each); partials reduced via LDS.
// ---------------------------------------------------------------------------
__global__ void __launch_bounds__(256, 1) rnn_scan(
    const float* __restrict__ E,
    const float* __restrict__ Wmm,
    unsigned* __restrict__ hbuf,     // [2][64][1024] packed (hi | lo<<16)
    float* __restrict__ out,
    unsigned* __restrict__ bar)      // 4 x {cnt,gen}, 16 uints apart
{
  __shared__ float part[4 * 16 * 33];   // [kq][m 16][n 32 (+1 pad)]

  const int tid = threadIdx.x;
  const int bg  = blockIdx.x >> 6;      // 0..3
  const int cg  = blockIdx.x & 63;      // 0..63
  const int b0  = bg << 4;              // batch base (16 per group)
  const int j0  = cg << 4;              // column base (16 col-pairs per block)

  const int kq = tid >> 6;              // wave = k-quarter
  const int lane = tid & 63;
  const int q = lane >> 4, ln = lane & 15;
  unsigned* mybar = bar + bg * 16;      // 64B apart

  // --- W_mm fragments, hi/lo bf16, VGPR-resident: [nt][ks] (nt0=a, nt1=c) ---
  short8 wh[2][8], wl[2][8];
#pragma unroll
  for (int nt = 0; nt < 2; ++nt) {
    const int row = (nt ? 1024 + j0 + ln : j0 + ln);
    const float* wp = Wmm + row * 1024 + kq * 256 + q * 8;
#pragma unroll
    for (int ks = 0; ks < 8; ++ks) {
      const float4 f0 = *(const float4*)(wp + ks * 32);
      const float4 f1 = *(const float4*)(wp + ks * 32 + 4);
      float f[8] = {f0.x, f0.y, f0.z, f0.w, f1.x, f1.y, f1.z, f1.w};
      short8 h8, l8;
#pragma unroll
      for (int e = 0; e < 8; ++e) {
        const unsigned short hh = f2bf(f[e]);
        h8[e] = (short)hh;
        l8[e] = (short)f2bf(f[e] - bf2f(hh));
      }
      wh[nt][ks] = h8; wl[nt][ks] = l8;
    }
  }

  // update-phase ownership: thread = (batch-local, col-local)
  const int b_l = tid >> 4, jp = tid & 15;
  const int b = b0 + b_l, j = j0 + jp;

  float h_reg = 0.0f;
  const unsigned* hrow_base0 = hbuf + (b0 + ln) * 1024 + kq * 256 + q * 8;

  for (int t = 0; t < 512; ++t) {
    const int cur = t & 1, nxt = cur ^ 1;

    // E loads issue early, consumed after the reduce (latency overlapped)
    const int erow = (b * 512 + t) * 3072 + j;
    const float ia = E[erow];
    const float ic = E[erow + 1024];
    const float io = E[erow + 2048];

    const unsigned* hrow = hrow_base0 + cur * 65536;

    floatx4 acc0 = (floatx4){0.f, 0.f, 0.f, 0.f};
    floatx4 acc1 = (floatx4){0.f, 0.f, 0.f, 0.f};
#pragma unroll
    for (int ks = 0; ks < 8; ++ks) {
      const uint4 p0 = *(const uint4*)(hrow + ks * 32);
      const uint4 p1 = *(const uint4*)(hrow + ks * 32 + 4);
      const unsigned pp[8] = {p0.x, p0.y, p0.z, p0.w, p1.x, p1.y, p1.z, p1.w};
      short8 ah, al;
#pragma unroll
      for (int e = 0; e < 8; ++e) {
        ah[e] = (short)(pp[e] & 0xffffu);
        al[e] = (short)(pp[e] >> 16);
      }
      acc0 = __builtin_amdgcn_mfma_f32_16x16x32_bf16(ah, wh[0][ks], acc0, 0, 0, 0);
      acc0 = __builtin_amdgcn_mfma_f32_16x16x32_bf16(al, wh[0][ks], acc0, 0, 0, 0);
      acc0 = __builtin_amdgcn_mfma_f32_16x16x32_bf16(ah, wl[0][ks], acc0, 0, 0, 0);
      acc1 = __builtin_amdgcn_mfma_f32_16x16x32_bf16(ah, wh[1][ks], acc1, 0, 0, 0);
      acc1 = __builtin_amdgcn_mfma_f32_16x16x32_bf16(al, wh[1][ks], acc1, 0, 0, 0);
      acc1 = __builtin_amdgcn_mfma_f32_16x16x32_bf16(ah, wl[1][ks], acc1, 0, 0, 0);
    }

    // C/D layout: col = lane&15 (n-local), row = q*4+r (m = batch-local)
#pragma unroll
    for (int r = 0; r < 4; ++r) {
      part[(kq * 16 + q * 4 + r) * 33 + ln]      = acc0[r];
      part[(kq * 16 + q * 4 + r) * 33 + 16 + ln] = acc1[r];
    }
    __syncthreads();

    const float m_a = part[(0 * 16 + b_l) * 33 + jp]      + part[(1 * 16 + b_l) * 33 + jp]
                    + part[(2 * 16 + b_l) * 33 + jp]      + part[(3 * 16 + b_l) * 33 + jp];
    const float m_c = part[(0 * 16 + b_l) * 33 + 16 + jp] + part[(1 * 16 + b_l) * 33 + 16 + jp]
                    + part[(2 * 16 + b_l) * 33 + 16 + jp] + part[(3 * 16 + b_l) * 33 + 16 + jp];

    const float av = 1.0f + tanhf(ia + m_a);
    const float cv = 1.0f / (1.0f + expf(-(ic + m_c)));
    const float hn = cv * h_reg + (1.0f - cv) * tanhf(io + av * h_reg);
    h_reg = hn;

    out[(b * 512 + t) * 1024 + j] = hn;
    const unsigned short hh = f2bf(hn);
    const unsigned short hl = f2bf(hn - bf2f(hh));
    hbuf[nxt * 65536 + b * 1024 + j] = (unsigned)hh | ((unsigned)hl << 16);

    group_barrier(mybar, 64, tid);
  }

  out[33554432 + b * 1024 + j] = h_reg;
}

// ---------------------------------------------------------------------------
extern "C" void kernel_launch(void* const* d_in, const int* in_sizes, int n_in,
                              void* d_out, int out_size, void* d_ws, size_t ws_size,
                              hipStream_t stream)
{
  const float* U   = (const float*)d_in[0];   // (64,512,512)
  const float* Wim = (const float*)d_in[1];   // (3072,512)
  const float* Wmm = (const float*)d_in[2];   // (2048,1024)
  float* out = (float*)d_out;                 // 33,554,432 + 65,536 fp32
  char* ws = (char*)d_ws;

  float* E = (float*)ws;
  unsigned* hbuf = (unsigned*)(ws + WS_HBUF_OFF);
  unsigned* bar  = (unsigned*)(ws + WS_BAR_OFF);

  // zero h ping-pong (h0 = 0) + the 4 group barriers (ws is poisoned 0xAA)
  hipMemsetAsync((void*)hbuf, 0, 524288 + 256, stream);

  gemm_in_proj<<<dim3(256, 24), dim3(256), 0, stream>>>(U, Wim, E);

  rnn_scan<<<dim3(256), dim3(256), 0, stream>>>(E, Wmm, hbuf, out, bar);
}

// Round 5
// 6593.246 us; speedup vs baseline: 2.5062x; 1.9994x over previous
//
#include <hip/hip_runtime.h>

// nBRC recurrent cell, B=64, L=512, IN=512, MEM=1024.
// Phase 1: E[32768][3072] = u @ W_im^T, bf16x3 split-precision MFMA (unchanged).
// Phase 2: 512-step scan, persistent kernel, 256 blocks = 4 independent groups
//   of 64 (group g owns batches [g*16,+16)). Block (bg,cg): 16 batches x 32
//   W-rows {j0..j0+15, 1024+j0..+15}, j0=cg*16; W hi/lo bf16 VGPR-resident.
// Sync (round-4 race fixed): producer ordering is now
//   h stores (sc0sc1, relaxed SYSTEM)
//   -> per-thread explicit s_waitcnt(0) (signal-fenced; every wave drains)
//   -> __syncthreads (join waves)
//   -> tid0 RELEASE store of flag at AGENT scope (emits buffer_wbl2 sc1 +
//      s_waitcnt vmcnt(0) + store sc1 = true global-visibility release).
//   wbl2 writes back dirty lines only (clean E lines stay cached); out[] is
//   stored cache-bypassing AFTER the flag so L2 stays clean and wbl2 is cheap.
//   Consumers poll relaxed (no inv -> E stays L2-resident); h loads are sc0sc1
//   so they cannot hit stale cached lines.
// Workspace layout (bytes):
//   [0, 402653184)            E (fp32)
//   [402653184, +524288)      hbuf: [2 pingpong][64][1024] packed (bf16 hi | lo<<16)
//   [403177472, +16384)       flags: [4 groups][64 blocks] uint, 64B stride
// Precision: GEMMs = hi*hi + lo*hi + hi*lo (bf16 splits), fp32 accum; h carried
// fp32 in owner registers. Measured absmax 3.9e-3 with this numerics path.

typedef __attribute__((ext_vector_type(8))) short short8;
typedef __attribute__((ext_vector_type(4))) float floatx4;

#define WS_HBUF_OFF 402653184UL
#define WS_FLAG_OFF 403177472UL

__device__ __forceinline__ unsigned short f2bf(float x) {
  unsigned u = __float_as_uint(x);
  unsigned r = (u + 0x7fffu + ((u >> 16) & 1u)) >> 16;  // RTN-even
  return (unsigned short)r;
}
__device__ __forceinline__ float bf2f(unsigned short h) {
  return __uint_as_float(((unsigned)h) << 16);
}

// ---------------------------------------------------------------------------
// Phase 1: E = U (32768x512, K-major) @ Wim^T (3072x512, K-major), fp32 out.
// ---------------------------------------------------------------------------
__global__ void __launch_bounds__(256, 2) gemm_in_proj(
    const float* __restrict__ U, const float* __restrict__ Wim,
    float* __restrict__ E)
{
  __shared__ unsigned short Ah[128][40], Al[128][40], Bh[128][40], Bl[128][40];
  const int tid = threadIdx.x;
  const int rbase = blockIdx.x * 128;
  const int nbase = blockIdx.y * 128;
  const int wave = tid >> 6, lane = tid & 63;
  const int wm = wave & 1, wn = wave >> 1;
  const int q = lane >> 4, ln = lane & 15;

  floatx4 acc[4][4];
#pragma unroll
  for (int mt = 0; mt < 4; ++mt)
#pragma unroll
    for (int nt = 0; nt < 4; ++nt)
      acc[mt][nt] = (floatx4){0.f, 0.f, 0.f, 0.f};

  for (int kc = 0; kc < 16; ++kc) {
    __syncthreads();
#pragma unroll
    for (int i = tid; i < 1024; i += 256) {
      const int row = i >> 3, c4 = (i & 7) << 2;
      const float4 va = *(const float4*)(U + (rbase + row) * 512 + kc * 32 + c4);
      const unsigned short a0 = f2bf(va.x), a1 = f2bf(va.y), a2 = f2bf(va.z), a3 = f2bf(va.w);
      *(ushort4*)&Ah[row][c4] = make_ushort4(a0, a1, a2, a3);
      *(ushort4*)&Al[row][c4] = make_ushort4(f2bf(va.x - bf2f(a0)), f2bf(va.y - bf2f(a1)),
                                             f2bf(va.z - bf2f(a2)), f2bf(va.w - bf2f(a3)));
      const float4 vb = *(const float4*)(Wim + (nbase + row) * 512 + kc * 32 + c4);
      const unsigned short b0 = f2bf(vb.x), b1 = f2bf(vb.y), b2 = f2bf(vb.z), b3 = f2bf(vb.w);
      *(ushort4*)&Bh[row][c4] = make_ushort4(b0, b1, b2, b3);
      *(ushort4*)&Bl[row][c4] = make_ushort4(f2bf(vb.x - bf2f(b0)), f2bf(vb.y - bf2f(b1)),
                                             f2bf(vb.z - bf2f(b2)), f2bf(vb.w - bf2f(b3)));
    }
    __syncthreads();

    short8 ah[4], al[4], bh[4], bl2[4];
#pragma unroll
    for (int mt = 0; mt < 4; ++mt) {
      const int m = wm * 64 + mt * 16 + ln;
      ah[mt] = *(const short8*)&Ah[m][q * 8];
      al[mt] = *(const short8*)&Al[m][q * 8];
    }
#pragma unroll
    for (int nt = 0; nt < 4; ++nt) {
      const int n = wn * 64 + nt * 16 + ln;
      bh[nt]  = *(const short8*)&Bh[n][q * 8];
      bl2[nt] = *(const short8*)&Bl[n][q * 8];
    }
#pragma unroll
    for (int mt = 0; mt < 4; ++mt)
#pragma unroll
      for (int nt = 0; nt < 4; ++nt) {
        acc[mt][nt] = __builtin_amdgcn_mfma_f32_16x16x32_bf16(ah[mt], bh[nt],  acc[mt][nt], 0, 0, 0);
        acc[mt][nt] = __builtin_amdgcn_mfma_f32_16x16x32_bf16(al[mt], bh[nt],  acc[mt][nt], 0, 0, 0);
        acc[mt][nt] = __builtin_amdgcn_mfma_f32_16x16x32_bf16(ah[mt], bl2[nt], acc[mt][nt], 0, 0, 0);
      }
  }

#pragma unroll
  for (int mt = 0; mt < 4; ++mt)
#pragma unroll
    for (int nt = 0; nt < 4; ++nt)
#pragma unroll
      for (int r = 0; r < 4; ++r) {
        const int gm = rbase + wm * 64 + mt * 16 + q * 4 + r;
        const int gn = nbase + wn * 64 + nt * 16 + ln;
        E[gm * 3072 + gn] = acc[mt][nt][r];
      }
}

// ---------------------------------------------------------------------------
// Phase 2: persistent scan, flag-synced. 256 blocks x 256 thr, 1 block/CU.
// ---------------------------------------------------------------------------
__global__ void __launch_bounds__(256, 1) rnn_scan(
    const float* __restrict__ E,
    const float* __restrict__ Wmm,
    unsigned* __restrict__ hbuf,     // [2][64][1024] packed (hi | lo<<16), sc0sc1
    float* __restrict__ out,
    unsigned* __restrict__ flags)    // [4][64] uints, 16-dword (64B) stride
{
  __shared__ float part[4 * 16 * 33];   // [kq][m 16][n 32 (+1 pad)]

  const int tid = threadIdx.x;
  const int bg  = blockIdx.x >> 6;      // 0..3 group
  const int cg  = blockIdx.x & 63;      // 0..63 block-in-group
  const int b0  = bg << 4;              // batch base (16 per group)
  const int j0  = cg << 4;              // column base

  const int kq = tid >> 6;              // wave = k-quarter
  const int lane = tid & 63;
  const int q = lane >> 4, ln = lane & 15;

  unsigned* gflags = flags + bg * 1024;            // 64 flags x 16 dwords
  unsigned* myflag = gflags + cg * 16;
  // wave kq consumes h cols [kq*256, +256) -> produced by blocks cg in [kq*16,+16)
  unsigned* pollp  = gflags + (kq * 16 + (lane & 15)) * 16;

  // --- W_mm fragments, hi/lo bf16, VGPR-resident: [nt][ks] (nt0=a, nt1=c) ---
  short8 wh[2][8], wl[2][8];
#pragma unroll
  for (int nt = 0; nt < 2; ++nt) {
    const int row = (nt ? 1024 + j0 + ln : j0 + ln);
    const float* wp = Wmm + row * 1024 + kq * 256 + q * 8;
#pragma unroll
    for (int ks = 0; ks < 8; ++ks) {
      const float4 f0 = *(const float4*)(wp + ks * 32);
      const float4 f1 = *(const float4*)(wp + ks * 32 + 4);
      float f[8] = {f0.x, f0.y, f0.z, f0.w, f1.x, f1.y, f1.z, f1.w};
      short8 h8, l8;
#pragma unroll
      for (int e = 0; e < 8; ++e) {
        const unsigned short hh = f2bf(f[e]);
        h8[e] = (short)hh;
        l8[e] = (short)f2bf(f[e] - bf2f(hh));
      }
      wh[nt][ks] = h8; wl[nt][ks] = l8;
    }
  }

  // update-phase ownership: thread = (batch-local, col-local)
  const int b_l = tid >> 4, jp = tid & 15;
  const int b = b0 + b_l, j = j0 + jp;

  float h_reg = 0.0f;
  // u64 index of this lane's h fragment base (dword idx / 2)
  const unsigned long long* hbuf64 = (const unsigned long long*)hbuf;
  const unsigned hbase64 = ((unsigned)(b0 + ln)) * 512 + (unsigned)kq * 128 + (unsigned)q * 4;

  for (int t = 0; t < 512; ++t) {
    const int cur = t & 1, nxt = cur ^ 1;

    // E loads issue early (plain, cacheable — E stays L2-resident, no inv ever)
    const int erow = (b * 512 + t) * 3072 + j;
    const float ia = E[erow];
    const float ic = E[erow + 1024];
    const float io = E[erow + 2048];

    // --- poll the 16 producer flags of this wave's k-quarter (>= t) ---
    {
      const unsigned target = (unsigned)t;
      unsigned v = __hip_atomic_load(pollp, __ATOMIC_RELAXED, __HIP_MEMORY_SCOPE_SYSTEM);
      while (!__all((int)(v >= target))) {
        __builtin_amdgcn_s_sleep(1);
        v = __hip_atomic_load(pollp, __ATOMIC_RELAXED, __HIP_MEMORY_SCOPE_SYSTEM);
      }
      __atomic_signal_fence(__ATOMIC_ACQUIRE);   // compiler: no hoisting h loads
    }

    const unsigned long long* hrow = hbuf64 + (unsigned)cur * 32768 + hbase64;

    floatx4 acc0 = (floatx4){0.f, 0.f, 0.f, 0.f};
    floatx4 acc1 = (floatx4){0.f, 0.f, 0.f, 0.f};
#pragma unroll
    for (int ks = 0; ks < 8; ++ks) {
      unsigned long long d0 = __hip_atomic_load((unsigned long long*)(hrow + ks * 16 + 0),
                                                __ATOMIC_RELAXED, __HIP_MEMORY_SCOPE_SYSTEM);
      unsigned long long d1 = __hip_atomic_load((unsigned long long*)(hrow + ks * 16 + 1),
                                                __ATOMIC_RELAXED, __HIP_MEMORY_SCOPE_SYSTEM);
      unsigned long long d2 = __hip_atomic_load((unsigned long long*)(hrow + ks * 16 + 2),
                                                __ATOMIC_RELAXED, __HIP_MEMORY_SCOPE_SYSTEM);
      unsigned long long d3 = __hip_atomic_load((unsigned long long*)(hrow + ks * 16 + 3),
                                                __ATOMIC_RELAXED, __HIP_MEMORY_SCOPE_SYSTEM);
      const unsigned pp[8] = {(unsigned)d0, (unsigned)(d0 >> 32),
                              (unsigned)d1, (unsigned)(d1 >> 32),
                              (unsigned)d2, (unsigned)(d2 >> 32),
                              (unsigned)d3, (unsigned)(d3 >> 32)};
      short8 ah, al;
#pragma unroll
      for (int e = 0; e < 8; ++e) {
        ah[e] = (short)(pp[e] & 0xffffu);
        al[e] = (short)(pp[e] >> 16);
      }
      acc0 = __builtin_amdgcn_mfma_f32_16x16x32_bf16(ah, wh[0][ks], acc0, 0, 0, 0);
      acc0 = __builtin_amdgcn_mfma_f32_16x16x32_bf16(al, wh[0][ks], acc0, 0, 0, 0);
      acc0 = __builtin_amdgcn_mfma_f32_16x16x32_bf16(ah, wl[0][ks], acc0, 0, 0, 0);
      acc1 = __builtin_amdgcn_mfma_f32_16x16x32_bf16(ah, wh[1][ks], acc1, 0, 0, 0);
      acc1 = __builtin_amdgcn_mfma_f32_16x16x32_bf16(al, wh[1][ks], acc1, 0, 0, 0);
      acc1 = __builtin_amdgcn_mfma_f32_16x16x32_bf16(ah, wl[1][ks], acc1, 0, 0, 0);
    }

    // C/D layout: col = lane&15 (n-local), row = q*4+r (m = batch-local)
#pragma unroll
    for (int r = 0; r < 4; ++r) {
      part[(kq * 16 + q * 4 + r) * 33 + ln]      = acc0[r];
      part[(kq * 16 + q * 4 + r) * 33 + 16 + ln] = acc1[r];
    }
    __syncthreads();   // sync(A): all polls passed + partials visible

    const float m_a = part[(0 * 16 + b_l) * 33 + jp]      + part[(1 * 16 + b_l) * 33 + jp]
                    + part[(2 * 16 + b_l) * 33 + jp]      + part[(3 * 16 + b_l) * 33 + jp];
    const float m_c = part[(0 * 16 + b_l) * 33 + 16 + jp] + part[(1 * 16 + b_l) * 33 + 16 + jp]
                    + part[(2 * 16 + b_l) * 33 + 16 + jp] + part[(3 * 16 + b_l) * 33 + 16 + jp];

    const float av = 1.0f + tanhf(ia + m_a);
    const float cv = 1.0f / (1.0f + expf(-(ic + m_c)));
    const float hn = cv * h_reg + (1.0f - cv) * tanhf(io + av * h_reg);
    h_reg = hn;

    const unsigned short hh = f2bf(hn);
    const unsigned short hl = f2bf(hn - bf2f(hh));
    __hip_atomic_store(hbuf + nxt * 65536 + b * 1024 + j,
                       (unsigned)hh | ((unsigned)hl << 16),
                       __ATOMIC_RELAXED, __HIP_MEMORY_SCOPE_SYSTEM);

    // --- release sequence: every wave drains its own h stores, then join,
    //     then tid0 publishes with a true agent-scope RELEASE (wbl2 + store) ---
    __atomic_signal_fence(__ATOMIC_SEQ_CST);
    __builtin_amdgcn_s_waitcnt(0);             // this wave: vmcnt(0) lgkmcnt(0)
    __atomic_signal_fence(__ATOMIC_SEQ_CST);
    __syncthreads();   // sync(B): all 4 waves' h stores drained & joined
    if (tid == 0)
      __hip_atomic_store(myflag, (unsigned)(t + 1),
                         __ATOMIC_RELEASE, __HIP_MEMORY_SCOPE_AGENT);

    // out[] store AFTER the flag: off the critical path; cache-bypassing so
    // L2 stays clean and the next release's wbl2 has nothing to flush.
    __hip_atomic_store(out + (unsigned)(b * 512 + t) * 1024 + (unsigned)j, hn,
                       __ATOMIC_RELAXED, __HIP_MEMORY_SCOPE_SYSTEM);
  }

  out[33554432 + b * 1024 + j] = h_reg;
}

// ---------------------------------------------------------------------------
extern "C" void kernel_launch(void* const* d_in, const int* in_sizes, int n_in,
                              void* d_out, int out_size, void* d_ws, size_t ws_size,
                              hipStream_t stream)
{
  const float* U   = (const float*)d_in[0];   // (64,512,512)
  const float* Wim = (const float*)d_in[1];   // (3072,512)
  const float* Wmm = (const float*)d_in[2];   // (2048,1024)
  float* out = (float*)d_out;                 // 33,554,432 + 65,536 fp32
  char* ws = (char*)d_ws;

  float* E = (float*)ws;
  unsigned* hbuf  = (unsigned*)(ws + WS_HBUF_OFF);
  unsigned* flags = (unsigned*)(ws + WS_FLAG_OFF);

  // zero h ping-pong (h0 = 0) + flags (monotonic, start at 0); ws poisoned 0xAA
  hipMemsetAsync((void*)hbuf, 0, 524288 + 16384, stream);

  gemm_in_proj<<<dim3(256, 24), dim3(256), 0, stream>>>(U, Wim, E);

  rnn_scan<<<dim3(256), dim3(256), 0, stream>>>(E, Wmm, hbuf, out, flags);
}